// Round 7
// baseline (202.054 us; speedup 1.0000x reference)
//
#include <hip/hip_runtime.h>
#include <hip/hip_bf16.h>

#define NEMB  4096
#define DIM   128
#define NROWS 32768
#define MARGIN 3.5e-4f   // >= 5x approx-error bound; validated r5-r8
#define RPB   128        // rows per block -> grid 256 = 1 block/CU
#define CHUNK 128        // codes per K-loop iteration
#define NITER 32         // NEMB/CHUNK

typedef _Float16 half8  __attribute__((ext_vector_type(8)));
typedef _Float16 half4v __attribute__((ext_vector_type(4)));
typedef _Float16 half2v __attribute__((ext_vector_type(2)));
typedef float    float16v __attribute__((ext_vector_type(16)));

typedef const __attribute__((address_space(1))) void* gas_ptr;
typedef __attribute__((address_space(3))) void*       las_ptr;

__device__ __forceinline__ void gload16(const void* g, void* l) {
    __builtin_amdgcn_global_load_lds((gas_ptr)g, (las_ptr)l, 16, 0, 0);
}

__device__ __forceinline__ half2v hmin2(half2v a, half2v b) {
    half2v r;
    r.x = (a.x < b.x) ? a.x : b.x;
    r.y = (a.y < b.y) ? a.y : b.y;
    return r;
}

// ---------------- K1: W -> fp16 (scale 2^16) in MFMA-fragment-major layout + ||w||^2 ----
// Wh2 layout: per (slab s = code/32, kchunk c = k/16): 1KB block; half index
// (s*8+c)*512 + (h*32 + (code&31))*8 + (k&7), h=(k>>3)&1.
__launch_bounds__(256)
__global__ void k_prep(const float* __restrict__ W, _Float16* __restrict__ Wh2,
                       float* __restrict__ sww, double* __restrict__ dsum,
                       int* __restrict__ cnt) {
    const int b = blockIdx.x;               // 512 blocks, 8 rows each
    const int t = threadIdx.x;
    const int rbase = b * 8;

    if (b == 0 && t == 0) { *dsum = 0.0; *cnt = 0; }   // loss accumulators

    const int i4 = rbase * 32 + t;
    const float4 v = ((const float4*)W)[i4];
    const int r  = i4 >> 5;
    const int k0 = (i4 & 31) * 4;
    const int s  = r >> 5, cs = r & 31, c = k0 >> 4, h2 = (k0 >> 3) & 1, j0 = k0 & 7;
    half4v hv = { (_Float16)(v.x * 65536.0f), (_Float16)(v.y * 65536.0f),
                  (_Float16)(v.z * 65536.0f), (_Float16)(v.w * 65536.0f) };
    *(half4v*)(Wh2 + (s * 8 + c) * 512 + (h2 * 32 + cs) * 8 + j0) = hv;

    if (t < 64) {   // numpy-pairwise ||w||^2 (exact fp32 semantics, validated r3-r8)
        const int row = rbase + (t >> 3);
        const int j   = t & 7;
        const float* p = W + (size_t)row * DIM + j;
        float vv = p[0];
        float rr = __fmul_rn(vv, vv);
        #pragma unroll
        for (int q = 1; q < 16; ++q) { vv = p[q * 8]; rr = __fadd_rn(rr, __fmul_rn(vv, vv)); }
        float o = __shfl_xor(rr, 1, 64); rr = __fadd_rn(rr, o);
        o = __shfl_xor(rr, 2, 64); rr = __fadd_rn(rr, o);
        o = __shfl_xor(rr, 4, 64); rr = __fadd_rn(rr, o);
        if (j == 0) sww[row] = rr;
    }
}

// ---------------- K2: R6 scan + 4-batched refine chains + fused loss (R15) ----------
// Scan: UNCHANGED (LDS-dbuf DMA, barrier-pipelined, 145->133us lineage).
// Refine: per wave, 8 rows processed as 2 batches of 4 -> gbuf reads, min-reduce
// stages and final argmin stages each run 4 independent chains (4x ILP on shfl
// latency).  Per-row item eval unchanged (bit-exact fmaf order).  Loss: block
// partials -> atomicAdd(double) + last-block writeout (k_lsum dispatch removed).
__global__ __launch_bounds__(1024, 4)
void k_main(const float* __restrict__ x, const _Float16* __restrict__ Wh2,
            const float* __restrict__ W, const float* __restrict__ sww,
            float* __restrict__ out0, float* __restrict__ out1,
            float* __restrict__ out_idx, double* __restrict__ dsum,
            int* __restrict__ cnt, float* __restrict__ out_loss) {
    __shared__ _Float16 sA[2 * CHUNK * DIM];   // 64 KB double buffer
    __shared__ _Float16 gbuf[RPB * 256];       // 64 KB group minima (swizzled)
    __shared__ float ssw[NEMB];                // 16 KB sww copy
    __shared__ float red16[16];                // block loss partials

    const int tid  = threadIdx.x;
    const int wv   = tid >> 6;      // 0..15
    const int lane = tid & 63;
    const int l31  = lane & 31;
    const int h    = lane >> 5;
    const int r0   = blockIdx.x * RPB;
    const int mt   = wv & 3;        // 32-code slab within chunk
    const int np   = wv >> 2;       // ntile 0..3 (rows np*32..np*32+31)

    ((float4*)ssw)[tid] = ((const float4*)sww)[tid];

    // B fragments: x rows of ntile np -> fp16 regs, B[n=lane&31][k=h*8+j] per 16-k chunk
    half8 bfr[8];
    {
        const float* xr = x + (size_t)(r0 + np * 32 + l31) * DIM + h * 8;
        #pragma unroll
        for (int c = 0; c < 8; ++c) {
            const float4 u0 = *(const float4*)(xr + c * 16);
            const float4 u1 = *(const float4*)(xr + c * 16 + 4);
            bfr[c] = (half8){ (_Float16)u0.x, (_Float16)u0.y, (_Float16)u0.z, (_Float16)u0.w,
                              (_Float16)u1.x, (_Float16)u1.y, (_Float16)u1.z, (_Float16)u1.w };
        }
    }

    // sxx (numpy-pairwise exact) for this wave's 8 refine rows, kept in regs
    float sxx_reg;
    {
        const float* ps = x + (size_t)(r0 + wv * 8 + (lane >> 3)) * DIM + (lane & 7);
        float vv = ps[0];
        float rr = __fmul_rn(vv, vv);
        #pragma unroll
        for (int q = 1; q < 16; ++q) { vv = ps[q * 8]; rr = __fadd_rn(rr, __fmul_rn(vv, vv)); }
        float o = __shfl_xor(rr, 1, 64); rr = __fadd_rn(rr, o);
        o = __shfl_xor(rr, 2, 64); rr = __fadd_rn(rr, o);
        o = __shfl_xor(rr, 4, 64); rr = __fadd_rn(rr, o);
        sxx_reg = rr;
    }

    // prologue DMA: chunk `start` -> buffer 0
    const int start = (blockIdx.x >> 3) & 31;
    {
        const char* src = (const char*)Wh2 + (size_t)start * (CHUNK * DIM * 2);
        #pragma unroll
        for (int r = 0; r < 2; ++r)
            gload16(src + wv * 2048 + r * 1024 + lane * 16, (char*)sA + wv * 2048 + r * 1024);
    }

    for (int it = 0; it < NITER; ++it) {
        __syncthreads();   // drains DMA issued one full iteration ago
        if (it + 1 < NITER) {
            const int nc = (start + it + 1) & (NITER - 1);
            const char* src = (const char*)Wh2 + (size_t)nc * (CHUNK * DIM * 2);
            char* dst = (char*)sA + ((it + 1) & 1) * (CHUNK * DIM * 2);
            #pragma unroll
            for (int r = 0; r < 2; ++r)
                gload16(src + wv * 2048 + r * 1024 + lane * 16, dst + wv * 2048 + r * 1024);
        }
        const int cb = (start + it) & (NITER - 1);

        const _Float16* curb = sA + (it & 1) * (CHUNK * DIM);
        float16v acc;
        #pragma unroll
        for (int i = 0; i < 16; ++i) acc[i] = 0.f;

        #pragma unroll
        for (int c = 0; c < 8; ++c) {
            const half8 a = *(const half8*)(curb + (mt * 8 + c) * 512 + lane * 8);
            acc = __builtin_amdgcn_mfma_f32_32x32x16_f16(a, bfr[c], acc, 0, 0, 0);
        }

        // epilogue: s~ = sww - acc*2^-15; two 16-code groups per slab; 1 shfl total
        const int s = cb * 4 + mt;   // global 32-code slab [0,128)
        const float4 swq0 = *(const float4*)((const char*)ssw + s * 128 + h * 16);
        const float4 swq1 = *(const float4*)((const char*)ssw + s * 128 + h * 16 + 32);
        const float4 swq2 = *(const float4*)((const char*)ssw + s * 128 + h * 16 + 64);
        const float4 swq3 = *(const float4*)((const char*)ssw + s * 128 + h * 16 + 96);
        float g0 = fmaf(acc[0], -0x1p-15f, swq0.x);
        g0 = fminf(g0, fmaf(acc[1], -0x1p-15f, swq0.y));
        g0 = fminf(g0, fmaf(acc[2], -0x1p-15f, swq0.z));
        g0 = fminf(g0, fmaf(acc[3], -0x1p-15f, swq0.w));
        g0 = fminf(g0, fmaf(acc[4], -0x1p-15f, swq1.x));
        g0 = fminf(g0, fmaf(acc[5], -0x1p-15f, swq1.y));
        g0 = fminf(g0, fmaf(acc[6], -0x1p-15f, swq1.z));
        g0 = fminf(g0, fmaf(acc[7], -0x1p-15f, swq1.w));
        float g1 = fmaf(acc[8], -0x1p-15f, swq2.x);
        g1 = fminf(g1, fmaf(acc[9],  -0x1p-15f, swq2.y));
        g1 = fminf(g1, fmaf(acc[10], -0x1p-15f, swq2.z));
        g1 = fminf(g1, fmaf(acc[11], -0x1p-15f, swq2.w));
        g1 = fminf(g1, fmaf(acc[12], -0x1p-15f, swq3.x));
        g1 = fminf(g1, fmaf(acc[13], -0x1p-15f, swq3.y));
        g1 = fminf(g1, fmaf(acc[14], -0x1p-15f, swq3.z));
        g1 = fminf(g1, fmaf(acc[15], -0x1p-15f, swq3.w));
        union { half2v h2; int u; } cu, ot;
        cu.h2.x = (_Float16)g0; cu.h2.y = (_Float16)g1;   // groups 2s, 2s+1
        ot.u = __shfl_xor(cu.u, 32, 64);
        cu.h2 = hmin2(cu.h2, ot.h2);
        if (h == 0) {
            const int row = np * 32 + l31;                // local row
            const int ws  = (s + row) & 127;              // swizzled word slot
            ((int*)gbuf)[row * 128 + ws] = cu.u;
        }
    }

    __syncthreads();

    // ---- fused flag + exact refine: 2 batches of 4 rows, chains 4-ILP (R15) ----
    const int cig = lane >> 2;
    const int kp  = lane & 3;
    float p_acc = 0.f;
    #pragma unroll
    for (int bb = 0; bb < 2; ++bb) {
        const int lr0 = wv * 8 + bb * 4;

        // batched gbuf reads + unpack
        int2 gw[4];
        #pragma unroll
        for (int t = 0; t < 4; ++t)
            gw[t] = *(const int2*)((const char*)gbuf + (lr0 + t) * 512 + lane * 8);
        float v0[4], v1[4], v2[4], v3[4], m_[4];
        #pragma unroll
        for (int t = 0; t < 4; ++t) {
            union { half2v h2; int u; } pa, pb;
            pa.u = gw[t].x; pb.u = gw[t].y;
            v0[t] = (float)pa.h2.x; v1[t] = (float)pa.h2.y;
            v2[t] = (float)pb.h2.x; v3[t] = (float)pb.h2.y;
            m_[t] = fminf(fminf(v0[t], v1[t]), fminf(v2[t], v3[t]));
        }
        // batched 6-stage min-reduce (4 independent chains per stage)
        #pragma unroll
        for (int off = 1; off < 64; off <<= 1) {
            #pragma unroll
            for (int t = 0; t < 4; ++t) m_[t] = fminf(m_[t], __shfl_xor(m_[t], off, 64));
        }
        float sxr[4];
        #pragma unroll
        for (int t = 0; t < 4; ++t) sxr[t] = __shfl(sxx_reg, (bb * 4 + t) * 8, 64);

        float bv[4]; int bi[4];
        #pragma unroll
        for (int t = 0; t < 4; ++t) { bv[t] = 3.0e38f; bi[t] = 0x7fffffff; }

        // per-row item eval (bit-exact R6 arithmetic)
        #pragma unroll
        for (int t = 0; t < 4; ++t) {
            const int lr  = lr0 + t;
            const int row = r0 + lr;
            const float thr = m_[t] + MARGIN;
            unsigned long long bal[4];
            bal[0] = __ballot(v0[t] <= thr);
            bal[1] = __ballot(v1[t] <= thr);
            bal[2] = __ballot(v2[t] <= thr);
            bal[3] = __ballot(v3[t] <= thr);

            const float* xr = x + (size_t)row * DIM;
            float4 xv[8];
            {
                const float4* xq4 = (const float4*)(xr + kp * 32);
                #pragma unroll
                for (int j2 = 0; j2 < 8; ++j2) xv[j2] = xq4[j2];
            }

            #pragma unroll
            for (int j = 0; j < 4; ++j) {
                unsigned long long msk = bal[j];
                while (msk) {
                    const int l = __builtin_ctzll(msk);
                    msk &= msk - 1;
                    const int wsl = 2 * l + (j >> 1);
                    const int g   = 2 * ((wsl - lr) & 127) + (j & 1);
                    const int c   = g * 16 + cig;
                    const float4* wq4 = (const float4*)(W + (size_t)c * DIM + kp * 32);
                    float dot = 0.f;
                    #pragma unroll
                    for (int j2 = 0; j2 < 8; ++j2) {
                        const float4 wv4 = wq4[j2];
                        dot = fmaf(xv[j2].x, wv4.x, dot);
                        dot = fmaf(xv[j2].y, wv4.y, dot);
                        dot = fmaf(xv[j2].z, wv4.z, dot);
                        dot = fmaf(xv[j2].w, wv4.w, dot);
                    }
                    float o = __shfl_xor(dot, 1, 64); dot = __fadd_rn(dot, o);
                    o = __shfl_xor(dot, 2, 64); dot = __fadd_rn(dot, o);
                    const float A = __fadd_rn(sxr[t], ssw[c]);
                    const float d = __fsub_rn(A, __fmul_rn(2.0f, dot));
                    if (d < bv[t] || (d == bv[t] && c < bi[t])) { bv[t] = d; bi[t] = c; }
                }
            }
        }

        // batched 6-stage argmin (4 independent chains per stage)
        #pragma unroll
        for (int off = 1; off < 64; off <<= 1) {
            #pragma unroll
            for (int t = 0; t < 4; ++t) {
                const float ov = __shfl_xor(bv[t], off, 64);
                const int   oi = __shfl_xor(bi[t], off, 64);
                if (ov < bv[t] || (ov == bv[t] && oi < bi[t])) { bv[t] = ov; bi[t] = oi; }
            }
        }

        // batched outputs
        #pragma unroll
        for (int t = 0; t < 4; ++t) {
            const int row = r0 + lr0 + t;
            const float* xr = x + (size_t)row * DIM;
            const float2 wv2 = *(const float2*)(W + (size_t)bi[t] * DIM + lane * 2);
            const float2 xv2 = *(const float2*)(xr + lane * 2);
            const float d0 = wv2.x - xv2.x, d1 = wv2.y - xv2.y;
            const float p = fmaf(d0, d0, d1 * d1);
            *(float2*)(out0 + (size_t)row * DIM + lane * 2) = wv2;
            *(float2*)(out1 + (size_t)row * DIM + lane * 2) = wv2;
            p_acc = __fadd_rn(p_acc, p);
            if (lane == 0) out_idx[row] = (float)bi[t];
        }
    }
    // wave partial -> block partial -> global double accumulate (loss)
    #pragma unroll
    for (int off = 32; off > 0; off >>= 1) p_acc += __shfl_down(p_acc, off, 64);
    if (lane == 0) red16[wv] = p_acc;
    __syncthreads();
    if (tid < 16) {
        float s = red16[tid];
        s += __shfl_xor(s, 1, 64);
        s += __shfl_xor(s, 2, 64);
        s += __shfl_xor(s, 4, 64);
        s += __shfl_xor(s, 8, 64);
        if (tid == 0) {
            atomicAdd(dsum, (double)s);
            __threadfence();
            const int prev = atomicAdd(cnt, 1);
            if (prev == (int)gridDim.x - 1) {
                __threadfence();
                const double tot = atomicAdd(dsum, 0.0);   // read full sum
                out_loss[0] = (float)(tot * (1.25 / ((double)NROWS * (double)DIM)));
            }
        }
    }
}

extern "C" void kernel_launch(void* const* d_in, const int* in_sizes, int n_in,
                              void* d_out, int out_size, void* d_ws, size_t ws_size,
                              hipStream_t stream) {
    const float* x = (const float*)d_in[0];   // [32768,128]
    const float* W = (const float*)d_in[1];   // [4096,128]
    float* out = (float*)d_out;

    float* out_q2d  = out;
    float* out_qst  = out + (size_t)NROWS * DIM;
    float* out_loss = out + (size_t)2 * NROWS * DIM;
    float* out_idx  = out + (size_t)2 * NROWS * DIM + 1;

    // ws layout: sww | dsum/cnt | Wh2  (~1.2 MB)
    float* ws   = (float*)d_ws;
    float* sww  = ws;                                   // 4096 floats
    double* dsum = (double*)(ws + 4096);                // 8B-aligned (16384B offset)
    int*    cnt  = (int*)(ws + 4098);
    _Float16* Wh2 = (_Float16*)(ws + 4096 + 32768);     // 4096*128 fp16, fragment-major

    k_prep<<<NEMB / 8, 256, 0, stream>>>(W, Wh2, sww, dsum, cnt);
    k_main<<<NROWS / RPB, 1024, 0, stream>>>(x, Wh2, W, sww,
                                             out_q2d, out_qst, out_idx,
                                             dsum, cnt, out_loss);
}

// Round 8
// 198.042 us; speedup vs baseline: 1.0203x; 1.0203x over previous
//
#include <hip/hip_runtime.h>
#include <hip/hip_bf16.h>

#define NEMB  4096
#define DIM   128
#define NROWS 32768
#define MARGIN 3.5e-4f   // >= 5x approx-error bound; validated r5-r8 (+1e-9 fold term)
#define RPB   128        // rows per block -> grid 256 = 1 block/CU
#define CHUNK 128        // codes per K-loop iteration
#define NITER 32         // NEMB/CHUNK

typedef _Float16 half8  __attribute__((ext_vector_type(8)));
typedef _Float16 half4v __attribute__((ext_vector_type(4)));
typedef _Float16 half2v __attribute__((ext_vector_type(2)));
typedef float    float16v __attribute__((ext_vector_type(16)));

typedef const __attribute__((address_space(1))) void* gas_ptr;
typedef __attribute__((address_space(3))) void*       las_ptr;

__device__ __forceinline__ void gload16(const void* g, void* l) {
    __builtin_amdgcn_global_load_lds((gas_ptr)g, (las_ptr)l, 16, 0, 0);
}

__device__ __forceinline__ half2v hmin2(half2v a, half2v b) {
    half2v r;
    r.x = (a.x < b.x) ? a.x : b.x;
    r.y = (a.y < b.y) ? a.y : b.y;
    return r;
}

// ---------------- K1: W -> fp16 (scale 2^16) fragment-major + ||w||^2 + swwh ----
// Wh2 layout: per (slab s = code/32, kchunk c = k/16): 1KB block; half index
// (s*8+c)*512 + (h*32 + (code&31))*8 + (k&7), h=(k>>3)&1.
// swwh[code] = fp16(sww*2^15) feeds the in-MFMA sww fold (R16).
__launch_bounds__(256)
__global__ void k_prep(const float* __restrict__ W, _Float16* __restrict__ Wh2,
                       float* __restrict__ sww, _Float16* __restrict__ swwh,
                       double* __restrict__ dsum, int* __restrict__ cnt) {
    const int b = blockIdx.x;               // 512 blocks, 8 rows each
    const int t = threadIdx.x;
    const int rbase = b * 8;

    if (b == 0 && t == 0) { *dsum = 0.0; *cnt = 0; }   // loss accumulators

    const int i4 = rbase * 32 + t;
    const float4 v = ((const float4*)W)[i4];
    const int r  = i4 >> 5;
    const int k0 = (i4 & 31) * 4;
    const int s  = r >> 5, cs = r & 31, c = k0 >> 4, h2 = (k0 >> 3) & 1, j0 = k0 & 7;
    half4v hv = { (_Float16)(v.x * 65536.0f), (_Float16)(v.y * 65536.0f),
                  (_Float16)(v.z * 65536.0f), (_Float16)(v.w * 65536.0f) };
    *(half4v*)(Wh2 + (s * 8 + c) * 512 + (h2 * 32 + cs) * 8 + j0) = hv;

    if (t < 64) {   // numpy-pairwise ||w||^2 (exact fp32 semantics, validated r3-r8)
        const int row = rbase + (t >> 3);
        const int j   = t & 7;
        const float* p = W + (size_t)row * DIM + j;
        float vv = p[0];
        float rr = __fmul_rn(vv, vv);
        #pragma unroll
        for (int q = 1; q < 16; ++q) { vv = p[q * 8]; rr = __fadd_rn(rr, __fmul_rn(vv, vv)); }
        float o = __shfl_xor(rr, 1, 64); rr = __fadd_rn(rr, o);
        o = __shfl_xor(rr, 2, 64); rr = __fadd_rn(rr, o);
        o = __shfl_xor(rr, 4, 64); rr = __fadd_rn(rr, o);
        if (j == 0) {
            sww[row]  = rr;
            swwh[row] = (_Float16)(rr * 32768.0f);   // sww*2^15, |err| ~ sww*2^-11
        }
    }
}

// ---------------- K2: R6 scan + in-MFMA sww fold (R16) + R6 refine + fused loss ----
// Scan: LDS-dbuf DMA (145->133us lineage) + 9th MFMA per acc folds -2^15*sww:
//   A_extra[code][0]=swwh[code], B_extra[row][0]=-1  =>  acc' = 2^16 x.w - 2^15 sww
//   group min = -2^-15 * max(acc'[0..7])  (max exact; 2^-15 scale exact).
// Deletes 4 ds_read_b128 (ssw) + 16 fmaf per wave-iteration from the hot loop.
// Refine: R6 unbatched (best measured).  Loss: R7 atomic fusion (no k_lsum).
__global__ __launch_bounds__(1024, 4)
void k_main(const float* __restrict__ x, const _Float16* __restrict__ Wh2,
            const float* __restrict__ W, const float* __restrict__ sww,
            const _Float16* __restrict__ swwh,
            float* __restrict__ out0, float* __restrict__ out1,
            float* __restrict__ out_idx, double* __restrict__ dsum,
            int* __restrict__ cnt, float* __restrict__ out_loss) {
    __shared__ _Float16 sA[2 * CHUNK * DIM];   // 64 KB double buffer
    __shared__ _Float16 gbuf[RPB * 256];       // 64 KB group minima (swizzled)
    __shared__ float ssw[NEMB];                // 16 KB sww copy (refine only now)
    __shared__ _Float16 swwh_lds[NEMB];        // 8 KB sww*2^15 fp16 (scan fold)
    __shared__ float red16[16];                // block loss partials

    const int tid  = threadIdx.x;
    const int wv   = tid >> 6;      // 0..15
    const int lane = tid & 63;
    const int l31  = lane & 31;
    const int h    = lane >> 5;
    const int r0   = blockIdx.x * RPB;
    const int mt   = wv & 3;        // 32-code slab within chunk
    const int np   = wv >> 2;       // ntile 0..3 (rows np*32..np*32+31)

    ((float4*)ssw)[tid] = ((const float4*)sww)[tid];
    if (tid < 512) ((float4*)swwh_lds)[tid] = ((const float4*)swwh)[tid];

    // B fragments: x rows of ntile np -> fp16 regs, B[n=lane&31][k=h*8+j] per 16-k chunk
    half8 bfr[8];
    {
        const float* xr = x + (size_t)(r0 + np * 32 + l31) * DIM + h * 8;
        #pragma unroll
        for (int c = 0; c < 8; ++c) {
            const float4 u0 = *(const float4*)(xr + c * 16);
            const float4 u1 = *(const float4*)(xr + c * 16 + 4);
            bfr[c] = (half8){ (_Float16)u0.x, (_Float16)u0.y, (_Float16)u0.z, (_Float16)u0.w,
                              (_Float16)u1.x, (_Float16)u1.y, (_Float16)u1.z, (_Float16)u1.w };
        }
    }

    // B_extra: B[row][k=0] = -1  (k=0 lives at h==0, j==0)
    half8 bx2 = (_Float16)0.0f;
    if (h == 0) bx2[0] = (_Float16)-1.0f;

    // sxx (numpy-pairwise exact) for this wave's 8 refine rows, kept in regs
    float sxx_reg;
    {
        const float* ps = x + (size_t)(r0 + wv * 8 + (lane >> 3)) * DIM + (lane & 7);
        float vv = ps[0];
        float rr = __fmul_rn(vv, vv);
        #pragma unroll
        for (int q = 1; q < 16; ++q) { vv = ps[q * 8]; rr = __fadd_rn(rr, __fmul_rn(vv, vv)); }
        float o = __shfl_xor(rr, 1, 64); rr = __fadd_rn(rr, o);
        o = __shfl_xor(rr, 2, 64); rr = __fadd_rn(rr, o);
        o = __shfl_xor(rr, 4, 64); rr = __fadd_rn(rr, o);
        sxx_reg = rr;
    }

    // prologue DMA: chunk `start` -> buffer 0
    const int start = (blockIdx.x >> 3) & 31;
    {
        const char* src = (const char*)Wh2 + (size_t)start * (CHUNK * DIM * 2);
        #pragma unroll
        for (int r = 0; r < 2; ++r)
            gload16(src + wv * 2048 + r * 1024 + lane * 16, (char*)sA + wv * 2048 + r * 1024);
    }

    for (int it = 0; it < NITER; ++it) {
        __syncthreads();   // drains DMA issued one full iteration ago
        if (it + 1 < NITER) {
            const int nc = (start + it + 1) & (NITER - 1);
            const char* src = (const char*)Wh2 + (size_t)nc * (CHUNK * DIM * 2);
            char* dst = (char*)sA + ((it + 1) & 1) * (CHUNK * DIM * 2);
            #pragma unroll
            for (int r = 0; r < 2; ++r)
                gload16(src + wv * 2048 + r * 1024 + lane * 16, dst + wv * 2048 + r * 1024);
        }
        const int cb = (start + it) & (NITER - 1);
        const int s  = cb * 4 + mt;   // global 32-code slab [0,128)

        // A_extra: A[code][k=0] = swwh[code]  (h==0, j==0 holds k=0)
        half8 ax = (_Float16)0.0f;
        if (h == 0) ax[0] = swwh_lds[s * 32 + l31];

        const _Float16* curb = sA + (it & 1) * (CHUNK * DIM);
        float16v acc;
        #pragma unroll
        for (int i = 0; i < 16; ++i) acc[i] = 0.f;

        #pragma unroll
        for (int c = 0; c < 8; ++c) {
            const half8 a = *(const half8*)(curb + (mt * 8 + c) * 512 + lane * 8);
            acc = __builtin_amdgcn_mfma_f32_32x32x16_f16(a, bfr[c], acc, 0, 0, 0);
        }
        // 9th MFMA: acc' = 2^16 x.w - 2^15 sww
        acc = __builtin_amdgcn_mfma_f32_32x32x16_f16(ax, bx2, acc, 0, 0, 0);

        // epilogue: group min = -2^-15 * max(acc'); max exact, scale exact
        const float mx0 = fmaxf(fmaxf(fmaxf(acc[0], acc[1]), fmaxf(acc[2], acc[3])),
                                fmaxf(fmaxf(acc[4], acc[5]), fmaxf(acc[6], acc[7])));
        const float mx1 = fmaxf(fmaxf(fmaxf(acc[8], acc[9]), fmaxf(acc[10], acc[11])),
                                fmaxf(fmaxf(acc[12], acc[13]), fmaxf(acc[14], acc[15])));
        const float g0 = mx0 * -0x1p-15f;
        const float g1 = mx1 * -0x1p-15f;
        union { half2v h2; int u; } cu, ot;
        cu.h2.x = (_Float16)g0; cu.h2.y = (_Float16)g1;   // groups 2s, 2s+1
        ot.u = __shfl_xor(cu.u, 32, 64);
        cu.h2 = hmin2(cu.h2, ot.h2);
        if (h == 0) {
            const int row = np * 32 + l31;                // local row
            const int ws  = (s + row) & 127;              // swizzled word slot
            ((int*)gbuf)[row * 128 + ws] = cu.u;
        }
    }

    __syncthreads();

    // ---- fused flag + exact refine (R6 form, best measured) ----
    const int cig = lane >> 2;
    const int kp  = lane & 3;
    float p_acc = 0.f;
    for (int t = 0; t < 8; ++t) {
        const int lr  = wv * 8 + t;
        const int row = r0 + lr;

        const int2 gw = *(const int2*)((const char*)gbuf + lr * 512 + lane * 8);
        union { half2v h2; int u; } pa, pb;
        pa.u = gw.x; pb.u = gw.y;
        const float v0 = (float)pa.h2.x, v1 = (float)pa.h2.y;
        const float v2 = (float)pb.h2.x, v3 = (float)pb.h2.y;
        float m = fminf(fminf(v0, v1), fminf(v2, v3));
        #pragma unroll
        for (int off = 1; off < 64; off <<= 1) m = fminf(m, __shfl_xor(m, off, 64));
        const float thr = m + MARGIN;
        unsigned long long bal[4];
        bal[0] = __ballot(v0 <= thr);
        bal[1] = __ballot(v1 <= thr);
        bal[2] = __ballot(v2 <= thr);
        bal[3] = __ballot(v3 <= thr);

        const float sxr = __shfl(sxx_reg, t * 8, 64);
        const float* xr = x + (size_t)row * DIM;

        // hoisted x quarter
        float4 xv[8];
        {
            const float4* xq4 = (const float4*)(xr + kp * 32);
            #pragma unroll
            for (int j2 = 0; j2 < 8; ++j2) xv[j2] = xq4[j2];
        }

        float bv = 3.0e38f;
        int   bi = 0x7fffffff;

        #pragma unroll
        for (int j = 0; j < 4; ++j) {
            unsigned long long msk = bal[j];
            while (msk) {
                const int l = __builtin_ctzll(msk);
                msk &= msk - 1;
                const int wsl = 2 * l + (j >> 1);
                const int g   = 2 * ((wsl - lr) & 127) + (j & 1);
                const int c   = g * 16 + cig;
                const float4* wq4 = (const float4*)(W + (size_t)c * DIM + kp * 32);
                float dot = 0.f;
                #pragma unroll
                for (int j2 = 0; j2 < 8; ++j2) {
                    const float4 wv4 = wq4[j2];
                    dot = fmaf(xv[j2].x, wv4.x, dot);
                    dot = fmaf(xv[j2].y, wv4.y, dot);
                    dot = fmaf(xv[j2].z, wv4.z, dot);
                    dot = fmaf(xv[j2].w, wv4.w, dot);
                }
                float o = __shfl_xor(dot, 1, 64); dot = __fadd_rn(dot, o);
                o = __shfl_xor(dot, 2, 64); dot = __fadd_rn(dot, o);
                const float A = __fadd_rn(sxr, ssw[c]);
                const float d = __fsub_rn(A, __fmul_rn(2.0f, dot));
                if (d < bv || (d == bv && c < bi)) { bv = d; bi = c; }
            }
        }
        #pragma unroll
        for (int off = 1; off < 64; off <<= 1) {
            const float ov = __shfl_xor(bv, off, 64);
            const int   oi = __shfl_xor(bi, off, 64);
            if (ov < bv || (ov == bv && oi < bi)) { bv = ov; bi = oi; }
        }

        const float2 wv2 = *(const float2*)(W + (size_t)bi * DIM + lane * 2);
        const float2 xv2 = *(const float2*)(xr + lane * 2);
        const float d0 = wv2.x - xv2.x, d1 = wv2.y - xv2.y;
        const float p = fmaf(d0, d0, d1 * d1);
        *(float2*)(out0 + (size_t)row * DIM + lane * 2) = wv2;
        *(float2*)(out1 + (size_t)row * DIM + lane * 2) = wv2;
        p_acc = __fadd_rn(p_acc, p);
        if (lane == 0) out_idx[row] = (float)bi;
    }
    // wave partial -> block partial -> global double accumulate (loss)
    #pragma unroll
    for (int off = 32; off > 0; off >>= 1) p_acc += __shfl_down(p_acc, off, 64);
    if (lane == 0) red16[wv] = p_acc;
    __syncthreads();
    if (tid < 16) {
        float sblk = red16[tid];
        sblk += __shfl_xor(sblk, 1, 64);
        sblk += __shfl_xor(sblk, 2, 64);
        sblk += __shfl_xor(sblk, 4, 64);
        sblk += __shfl_xor(sblk, 8, 64);
        if (tid == 0) {
            atomicAdd(dsum, (double)sblk);
            __threadfence();
            const int prev = atomicAdd(cnt, 1);
            if (prev == (int)gridDim.x - 1) {
                __threadfence();
                const double tot = atomicAdd(dsum, 0.0);   // read full sum
                out_loss[0] = (float)(tot * (1.25 / ((double)NROWS * (double)DIM)));
            }
        }
    }
}

extern "C" void kernel_launch(void* const* d_in, const int* in_sizes, int n_in,
                              void* d_out, int out_size, void* d_ws, size_t ws_size,
                              hipStream_t stream) {
    const float* x = (const float*)d_in[0];   // [32768,128]
    const float* W = (const float*)d_in[1];   // [4096,128]
    float* out = (float*)d_out;

    float* out_q2d  = out;
    float* out_qst  = out + (size_t)NROWS * DIM;
    float* out_loss = out + (size_t)2 * NROWS * DIM;
    float* out_idx  = out + (size_t)2 * NROWS * DIM + 1;

    // ws layout (floats): sww[0..4096) | dsum@4096 cnt@4098 | swwh@8192 (8KB) | Wh2@36864
    float* ws   = (float*)d_ws;
    float* sww  = ws;
    double* dsum = (double*)(ws + 4096);                // byte 16384, 8-aligned
    int*    cnt  = (int*)(ws + 4098);
    _Float16* swwh = (_Float16*)(ws + 8192);            // 4096 halfs
    _Float16* Wh2  = (_Float16*)(ws + 4096 + 32768);    // 4096*128 fp16, fragment-major

    k_prep<<<NEMB / 8, 256, 0, stream>>>(W, Wh2, sww, swwh, dsum, cnt);
    k_main<<<NROWS / RPB, 1024, 0, stream>>>(x, Wh2, W, sww, swwh,
                                             out_q2d, out_qst, out_idx,
                                             dsum, cnt, out_loss);
}

// Round 9
// 172.546 us; speedup vs baseline: 1.1710x; 1.1478x over previous
//
#include <hip/hip_runtime.h>
#include <hip/hip_bf16.h>

#define NEMB  4096
#define DIM   128
#define NROWS 32768
#define MARGIN 3.5e-4f   // >= 5x approx-error bound; validated r5-r8 (+1e-9 fold term)
#define RPB   128        // rows per block -> grid 256 = 1 block/CU
#define CHUNK 128        // codes per K-loop iteration
#define NITER 32         // NEMB/CHUNK

typedef _Float16 half8  __attribute__((ext_vector_type(8)));
typedef _Float16 half4v __attribute__((ext_vector_type(4)));
typedef _Float16 half2v __attribute__((ext_vector_type(2)));
typedef float    float16v __attribute__((ext_vector_type(16)));

typedef const __attribute__((address_space(1))) void* gas_ptr;
typedef __attribute__((address_space(3))) void*       las_ptr;

__device__ __forceinline__ void gload16(const void* g, void* l) {
    __builtin_amdgcn_global_load_lds((gas_ptr)g, (las_ptr)l, 16, 0, 0);
}

__device__ __forceinline__ half2v hmin2(half2v a, half2v b) {
    half2v r;
    r.x = (a.x < b.x) ? a.x : b.x;
    r.y = (a.y < b.y) ? a.y : b.y;
    return r;
}

// ---------------- K1: W -> fp16 (scale 2^16) fragment-major + ||w||^2 + swwh ----
// Wh2 layout: per (slab s = code/32, kchunk c = k/16): 1KB block; half index
// (s*8+c)*512 + (h*32 + (code&31))*8 + (k&7), h=(k>>3)&1.
// swwh[code] = fp16(sww*2^15) feeds the in-MFMA sww fold (R16).
__launch_bounds__(256)
__global__ void k_prep(const float* __restrict__ W, _Float16* __restrict__ Wh2,
                       float* __restrict__ sww, _Float16* __restrict__ swwh,
                       double* __restrict__ dsum, int* __restrict__ cnt) {
    const int b = blockIdx.x;               // 512 blocks, 8 rows each
    const int t = threadIdx.x;
    const int rbase = b * 8;

    if (b == 0 && t == 0) { *dsum = 0.0; *cnt = 0; }   // loss accumulators

    const int i4 = rbase * 32 + t;
    const float4 v = ((const float4*)W)[i4];
    const int r  = i4 >> 5;
    const int k0 = (i4 & 31) * 4;
    const int s  = r >> 5, cs = r & 31, c = k0 >> 4, h2 = (k0 >> 3) & 1, j0 = k0 & 7;
    half4v hv = { (_Float16)(v.x * 65536.0f), (_Float16)(v.y * 65536.0f),
                  (_Float16)(v.z * 65536.0f), (_Float16)(v.w * 65536.0f) };
    *(half4v*)(Wh2 + (s * 8 + c) * 512 + (h2 * 32 + cs) * 8 + j0) = hv;

    if (t < 64) {   // numpy-pairwise ||w||^2 (exact fp32 semantics, validated r3-r8)
        const int row = rbase + (t >> 3);
        const int j   = t & 7;
        const float* p = W + (size_t)row * DIM + j;
        float vv = p[0];
        float rr = __fmul_rn(vv, vv);
        #pragma unroll
        for (int q = 1; q < 16; ++q) { vv = p[q * 8]; rr = __fadd_rn(rr, __fmul_rn(vv, vv)); }
        float o = __shfl_xor(rr, 1, 64); rr = __fadd_rn(rr, o);
        o = __shfl_xor(rr, 2, 64); rr = __fadd_rn(rr, o);
        o = __shfl_xor(rr, 4, 64); rr = __fadd_rn(rr, o);
        if (j == 0) {
            sww[row]  = rr;
            swwh[row] = (_Float16)(rr * 32768.0f);   // sww*2^15, |err| ~ sww*2^-11
        }
    }
}

// ---------------- K2: R8 scan (in-MFMA sww fold) + x-in-LDS refine (R17) ----------
// Scan: unchanged from R8.  After the scan, the dead 64 KB sA buffer is refilled
// with the block's 128 x-rows (fp32, coalesced copy); refine reads xv[]/xv2 from
// LDS instead of global -> removes ~50 L2-latency transactions per serial
// row-chain.  Values bitwise identical (pure copy).
__global__ __launch_bounds__(1024, 4)
void k_main(const float* __restrict__ x, const _Float16* __restrict__ Wh2,
            const float* __restrict__ W, const float* __restrict__ sww,
            const _Float16* __restrict__ swwh,
            float* __restrict__ out0, float* __restrict__ out1,
            float* __restrict__ out_idx, double* __restrict__ dsum,
            int* __restrict__ cnt, float* __restrict__ out_loss) {
    __shared__ __align__(16) _Float16 sA[2 * CHUNK * DIM];   // 64 KB dbuf / x-cache
    __shared__ _Float16 gbuf[RPB * 256];       // 64 KB group minima (swizzled)
    __shared__ float ssw[NEMB];                // 16 KB sww copy (refine only)
    __shared__ _Float16 swwh_lds[NEMB];        // 8 KB sww*2^15 fp16 (scan fold)
    __shared__ float red16[16];                // block loss partials

    const int tid  = threadIdx.x;
    const int wv   = tid >> 6;      // 0..15
    const int lane = tid & 63;
    const int l31  = lane & 31;
    const int h    = lane >> 5;
    const int r0   = blockIdx.x * RPB;
    const int mt   = wv & 3;        // 32-code slab within chunk
    const int np   = wv >> 2;       // ntile 0..3 (rows np*32..np*32+31)

    ((float4*)ssw)[tid] = ((const float4*)sww)[tid];
    if (tid < 512) ((float4*)swwh_lds)[tid] = ((const float4*)swwh)[tid];

    // B fragments: x rows of ntile np -> fp16 regs, B[n=lane&31][k=h*8+j] per 16-k chunk
    half8 bfr[8];
    {
        const float* xr = x + (size_t)(r0 + np * 32 + l31) * DIM + h * 8;
        #pragma unroll
        for (int c = 0; c < 8; ++c) {
            const float4 u0 = *(const float4*)(xr + c * 16);
            const float4 u1 = *(const float4*)(xr + c * 16 + 4);
            bfr[c] = (half8){ (_Float16)u0.x, (_Float16)u0.y, (_Float16)u0.z, (_Float16)u0.w,
                              (_Float16)u1.x, (_Float16)u1.y, (_Float16)u1.z, (_Float16)u1.w };
        }
    }

    // B_extra: B[row][k=0] = -1  (k=0 lives at h==0, j==0)
    half8 bx2 = (_Float16)0.0f;
    if (h == 0) bx2[0] = (_Float16)-1.0f;

    // sxx (numpy-pairwise exact) for this wave's 8 refine rows, kept in regs
    float sxx_reg;
    {
        const float* ps = x + (size_t)(r0 + wv * 8 + (lane >> 3)) * DIM + (lane & 7);
        float vv = ps[0];
        float rr = __fmul_rn(vv, vv);
        #pragma unroll
        for (int q = 1; q < 16; ++q) { vv = ps[q * 8]; rr = __fadd_rn(rr, __fmul_rn(vv, vv)); }
        float o = __shfl_xor(rr, 1, 64); rr = __fadd_rn(rr, o);
        o = __shfl_xor(rr, 2, 64); rr = __fadd_rn(rr, o);
        o = __shfl_xor(rr, 4, 64); rr = __fadd_rn(rr, o);
        sxx_reg = rr;
    }

    // prologue DMA: chunk `start` -> buffer 0
    const int start = (blockIdx.x >> 3) & 31;
    {
        const char* src = (const char*)Wh2 + (size_t)start * (CHUNK * DIM * 2);
        #pragma unroll
        for (int r = 0; r < 2; ++r)
            gload16(src + wv * 2048 + r * 1024 + lane * 16, (char*)sA + wv * 2048 + r * 1024);
    }

    for (int it = 0; it < NITER; ++it) {
        __syncthreads();   // drains DMA issued one full iteration ago
        if (it + 1 < NITER) {
            const int nc = (start + it + 1) & (NITER - 1);
            const char* src = (const char*)Wh2 + (size_t)nc * (CHUNK * DIM * 2);
            char* dst = (char*)sA + ((it + 1) & 1) * (CHUNK * DIM * 2);
            #pragma unroll
            for (int r = 0; r < 2; ++r)
                gload16(src + wv * 2048 + r * 1024 + lane * 16, dst + wv * 2048 + r * 1024);
        }
        const int cb = (start + it) & (NITER - 1);
        const int s  = cb * 4 + mt;   // global 32-code slab [0,128)

        // A_extra: A[code][k=0] = swwh[code]  (h==0, j==0 holds k=0)
        half8 ax = (_Float16)0.0f;
        if (h == 0) ax[0] = swwh_lds[s * 32 + l31];

        const _Float16* curb = sA + (it & 1) * (CHUNK * DIM);
        float16v acc;
        #pragma unroll
        for (int i = 0; i < 16; ++i) acc[i] = 0.f;

        #pragma unroll
        for (int c = 0; c < 8; ++c) {
            const half8 a = *(const half8*)(curb + (mt * 8 + c) * 512 + lane * 8);
            acc = __builtin_amdgcn_mfma_f32_32x32x16_f16(a, bfr[c], acc, 0, 0, 0);
        }
        // 9th MFMA: acc' = 2^16 x.w - 2^15 sww
        acc = __builtin_amdgcn_mfma_f32_32x32x16_f16(ax, bx2, acc, 0, 0, 0);

        // epilogue: group min = -2^-15 * max(acc'); max exact, scale exact
        const float mx0 = fmaxf(fmaxf(fmaxf(acc[0], acc[1]), fmaxf(acc[2], acc[3])),
                                fmaxf(fmaxf(acc[4], acc[5]), fmaxf(acc[6], acc[7])));
        const float mx1 = fmaxf(fmaxf(fmaxf(acc[8], acc[9]), fmaxf(acc[10], acc[11])),
                                fmaxf(fmaxf(acc[12], acc[13]), fmaxf(acc[14], acc[15])));
        const float g0 = mx0 * -0x1p-15f;
        const float g1 = mx1 * -0x1p-15f;
        union { half2v h2; int u; } cu, ot;
        cu.h2.x = (_Float16)g0; cu.h2.y = (_Float16)g1;   // groups 2s, 2s+1
        ot.u = __shfl_xor(cu.u, 32, 64);
        cu.h2 = hmin2(cu.h2, ot.h2);
        if (h == 0) {
            const int row = np * 32 + l31;                // local row
            const int ws  = (s + row) & 127;              // swizzled word slot
            ((int*)gbuf)[row * 128 + ws] = cu.u;
        }
    }

    __syncthreads();   // scan complete; sA (DMA buffer) now dead

    // ---- R17: refill sA with the block's x rows (64 KB fp32, coalesced) ----
    {
        float4* sAf4 = (float4*)sA;
        const float4* xg4 = (const float4*)(x + (size_t)r0 * DIM);
        #pragma unroll
        for (int i = 0; i < 4; ++i) sAf4[tid + i * 1024] = xg4[tid + i * 1024];
    }
    __syncthreads();
    const float* sAf = (const float*)sA;

    // ---- fused flag + exact refine (R6 form; x served from LDS) ----
    const int cig = lane >> 2;
    const int kp  = lane & 3;
    float p_acc = 0.f;
    for (int t = 0; t < 8; ++t) {
        const int lr  = wv * 8 + t;
        const int row = r0 + lr;

        const int2 gw = *(const int2*)((const char*)gbuf + lr * 512 + lane * 8);
        union { half2v h2; int u; } pa, pb;
        pa.u = gw.x; pb.u = gw.y;
        const float v0 = (float)pa.h2.x, v1 = (float)pa.h2.y;
        const float v2 = (float)pb.h2.x, v3 = (float)pb.h2.y;
        float m = fminf(fminf(v0, v1), fminf(v2, v3));
        #pragma unroll
        for (int off = 1; off < 64; off <<= 1) m = fminf(m, __shfl_xor(m, off, 64));
        const float thr = m + MARGIN;
        unsigned long long bal[4];
        bal[0] = __ballot(v0 <= thr);
        bal[1] = __ballot(v1 <= thr);
        bal[2] = __ballot(v2 <= thr);
        bal[3] = __ballot(v3 <= thr);

        const float sxr = __shfl(sxx_reg, t * 8, 64);
        const float* xl = sAf + lr * DIM;    // this row's x, in LDS

        // hoisted x quarter (from LDS; 16-lane same-address -> broadcast)
        float4 xv[8];
        {
            const float4* xq4 = (const float4*)(xl + kp * 32);
            #pragma unroll
            for (int j2 = 0; j2 < 8; ++j2) xv[j2] = xq4[j2];
        }

        float bv = 3.0e38f;
        int   bi = 0x7fffffff;

        #pragma unroll
        for (int j = 0; j < 4; ++j) {
            unsigned long long msk = bal[j];
            while (msk) {
                const int l = __builtin_ctzll(msk);
                msk &= msk - 1;
                const int wsl = 2 * l + (j >> 1);
                const int g   = 2 * ((wsl - lr) & 127) + (j & 1);
                const int c   = g * 16 + cig;
                const float4* wq4 = (const float4*)(W + (size_t)c * DIM + kp * 32);
                float dot = 0.f;
                #pragma unroll
                for (int j2 = 0; j2 < 8; ++j2) {
                    const float4 wv4 = wq4[j2];
                    dot = fmaf(xv[j2].x, wv4.x, dot);
                    dot = fmaf(xv[j2].y, wv4.y, dot);
                    dot = fmaf(xv[j2].z, wv4.z, dot);
                    dot = fmaf(xv[j2].w, wv4.w, dot);
                }
                float o = __shfl_xor(dot, 1, 64); dot = __fadd_rn(dot, o);
                o = __shfl_xor(dot, 2, 64); dot = __fadd_rn(dot, o);
                const float A = __fadd_rn(sxr, ssw[c]);
                const float d = __fsub_rn(A, __fmul_rn(2.0f, dot));
                if (d < bv || (d == bv && c < bi)) { bv = d; bi = c; }
            }
        }
        #pragma unroll
        for (int off = 1; off < 64; off <<= 1) {
            const float ov = __shfl_xor(bv, off, 64);
            const int   oi = __shfl_xor(bi, off, 64);
            if (ov < bv || (ov == bv && oi < bi)) { bv = ov; bi = oi; }
        }

        const float2 wv2 = *(const float2*)(W + (size_t)bi * DIM + lane * 2);
        const float2 xv2 = *(const float2*)(xl + lane * 2);
        const float d0 = wv2.x - xv2.x, d1 = wv2.y - xv2.y;
        const float p = fmaf(d0, d0, d1 * d1);
        *(float2*)(out0 + (size_t)row * DIM + lane * 2) = wv2;
        *(float2*)(out1 + (size_t)row * DIM + lane * 2) = wv2;
        p_acc = __fadd_rn(p_acc, p);
        if (lane == 0) out_idx[row] = (float)bi;
    }
    // wave partial -> block partial -> global double accumulate (loss)
    #pragma unroll
    for (int off = 32; off > 0; off >>= 1) p_acc += __shfl_down(p_acc, off, 64);
    if (lane == 0) red16[wv] = p_acc;
    __syncthreads();
    if (tid < 16) {
        float sblk = red16[tid];
        sblk += __shfl_xor(sblk, 1, 64);
        sblk += __shfl_xor(sblk, 2, 64);
        sblk += __shfl_xor(sblk, 4, 64);
        sblk += __shfl_xor(sblk, 8, 64);
        if (tid == 0) {
            atomicAdd(dsum, (double)sblk);
            __threadfence();
            const int prev = atomicAdd(cnt, 1);
            if (prev == (int)gridDim.x - 1) {
                __threadfence();
                const double tot = atomicAdd(dsum, 0.0);   // read full sum
                out_loss[0] = (float)(tot * (1.25 / ((double)NROWS * (double)DIM)));
            }
        }
    }
}

extern "C" void kernel_launch(void* const* d_in, const int* in_sizes, int n_in,
                              void* d_out, int out_size, void* d_ws, size_t ws_size,
                              hipStream_t stream) {
    const float* x = (const float*)d_in[0];   // [32768,128]
    const float* W = (const float*)d_in[1];   // [4096,128]
    float* out = (float*)d_out;

    float* out_q2d  = out;
    float* out_qst  = out + (size_t)NROWS * DIM;
    float* out_loss = out + (size_t)2 * NROWS * DIM;
    float* out_idx  = out + (size_t)2 * NROWS * DIM + 1;

    // ws layout (floats): sww[0..4096) | dsum@4096 cnt@4098 | swwh@8192 (8KB) | Wh2@36864
    float* ws   = (float*)d_ws;
    float* sww  = ws;
    double* dsum = (double*)(ws + 4096);                // byte 16384, 8-aligned
    int*    cnt  = (int*)(ws + 4098);
    _Float16* swwh = (_Float16*)(ws + 8192);            // 4096 halfs
    _Float16* Wh2  = (_Float16*)(ws + 4096 + 32768);    // 4096*128 fp16, fragment-major

    k_prep<<<NEMB / 8, 256, 0, stream>>>(W, Wh2, sww, swwh, dsum, cnt);
    k_main<<<NROWS / RPB, 1024, 0, stream>>>(x, Wh2, W, sww, swwh,
                                             out_q2d, out_qst, out_idx,
                                             dsum, cnt, out_loss);
}